// Round 2
// baseline (2105.892 us; speedup 1.0000x reference)
//
#include <hip/hip_runtime.h>

// MoE fused kernel, MI355X (gfx950).
// N=524288 tokens, D=128, E=8, top-2 routing.
// Strategy: dense all-8-expert f16 MFMA with fp32 masked-gate fold in epilogue.
// Block = 512 threads (8 waves), 256 tokens/block, grid 2048.
// Wave tiling: wm=wid>>1 picks 64-token group (4 m-tiles of 16),
//              wn=wid&1 picks 64-feature half (4 n-tiles of 16).

typedef _Float16 half8 __attribute__((ext_vector_type(8)));
typedef float    f32x4 __attribute__((ext_vector_type(4)));

#define N_TOK   524288
#define TPB     256      // tokens per block

__global__ __launch_bounds__(512, 2)
void moe_fused(const float* __restrict__ x,
               const float* __restrict__ gW,
               const float* __restrict__ gb,
               const float* __restrict__ W,
               const float* __restrict__ b,
               float* __restrict__ out)
{
    const int tid  = threadIdx.x;
    const int lane = tid & 63;
    const int wid  = tid >> 6;      // 0..7
    const int wm   = wid >> 1;      // 0..3 : which 64-token group
    const int wn   = wid & 1;       // 0..1 : which 64-feature half
    const int r16  = lane & 15;     // A-row / B-col / D-col within tile
    const int q    = lane >> 4;     // 0..3 : k-group (k = q*8..q*8+7)

    const int  t0w = wm * 64;                       // token offset in block
    const long tb  = (long)blockIdx.x * TPB;        // block token base

    __shared__ __align__(16) float     gW_s[8 * 128];          // 4 KB
    __shared__             float       gb_s[8];
    __shared__ __align__(16) float     c_s[8][256];            // 8 KB  masked gate weights
    __shared__ __align__(16) _Float16  gA_s[256 * 32];         // 16 KB g (all experts), K-padded to 32
    __shared__ __align__(16) _Float16  bB_s[128 * 32];         // 8 KB  b as B-operand, K-padded
    __shared__ __align__(16) _Float16  wb_s[2][128 * 128];     // 64 KB W_e double buffer (swizzled)

    // ---------------- phase 0: stage gate weights / bias ----------------
    ((float2*)gW_s)[tid] = ((const float2*)gW)[tid];   // 1024 floats
    if (tid < 8) gb_s[tid] = gb[tid];
    for (int i = tid; i < 128 * 32; i += 512) {
        int f = i >> 5, k = i & 31;
        bB_s[i] = (k < 8) ? (_Float16)b[k * 128 + f] : (_Float16)0.f;
    }
    __syncthreads();

    // ---------------- issue expert-0 W loads (in flight through gate) ----
    f32x4 st[4][2];
    {
        const f32x4* wsrc = (const f32x4*)W;
        #pragma unroll
        for (int it = 0; it < 4; ++it) {
            int v = it * 512 + tid;                  // vec8 index 0..2047
            st[it][0] = wsrc[v * 2 + 0];
            st[it][1] = wsrc[v * 2 + 1];
        }
    }

    // ---------------- phase 1: load x -> f16 A-frags + fp32 gate partials
    half8 af[4][4];
    float plog[4][8];
    #pragma unroll
    for (int m = 0; m < 4; ++m)
        #pragma unroll
        for (int e = 0; e < 8; ++e) plog[m][e] = 0.f;

    #pragma unroll
    for (int m = 0; m < 4; ++m) {
        const long tok = tb + t0w + m * 16 + r16;    // A-frag row = lane&15
        const float* xr = x + tok * 128;
        #pragma unroll
        for (int k = 0; k < 4; ++k) {
            const int col = k * 32 + q * 8;          // A-frag k = (lane>>4)*8 + j
            f32x4 v0 = *(const f32x4*)(xr + col);
            f32x4 v1 = *(const f32x4*)(xr + col + 4);
            half8 pk;
            pk[0]=(_Float16)v0[0]; pk[1]=(_Float16)v0[1]; pk[2]=(_Float16)v0[2]; pk[3]=(_Float16)v0[3];
            pk[4]=(_Float16)v1[0]; pk[5]=(_Float16)v1[1]; pk[6]=(_Float16)v1[2]; pk[7]=(_Float16)v1[3];
            af[m][k] = pk;
            #pragma unroll
            for (int e = 0; e < 8; ++e) {            // exact fp32 gate partials
                const float* g = gW_s + e * 128 + col;
                plog[m][e] += v0[0]*g[0] + v0[1]*g[1] + v0[2]*g[2] + v0[3]*g[3]
                            + v1[0]*g[4] + v1[1]*g[5] + v1[2]*g[6] + v1[3]*g[7];
            }
        }
    }

    // ---------------- phase 2: gate reduce + softmax + top-2 -------------
    #pragma unroll
    for (int m = 0; m < 4; ++m) {
        #pragma unroll
        for (int e = 0; e < 8; ++e) {
            float v = plog[m][e];
            v += __shfl_xor(v, 16, 64);              // sum over q-groups
            v += __shfl_xor(v, 32, 64);
            plog[m][e] = v + gb_s[e];
        }
        float m1 = -1e30f; int i1 = 0;
        #pragma unroll
        for (int e = 0; e < 8; ++e) if (plog[m][e] > m1) { m1 = plog[m][e]; i1 = e; }
        float m2 = -1e30f; int i2 = (i1 == 0) ? 1 : 0;
        #pragma unroll
        for (int e = 0; e < 8; ++e) if (e != i1 && plog[m][e] > m2) { m2 = plog[m][e]; i2 = e; }
        float ge[8]; float sum = 0.f;
        #pragma unroll
        for (int e = 0; e < 8; ++e) { ge[e] = __expf(plog[m][e] - m1); sum += ge[e]; }
        const float inv = 1.f / sum;
        if (q == 0 && wn == 0) {                     // one writer per token
            const int row = t0w + m * 16 + r16;
            half8 pg;
            #pragma unroll
            for (int e = 0; e < 8; ++e) {
                float gg = ge[e] * inv;
                c_s[e][row] = (e == i1 || e == i2) ? gg : 0.f;
                pg[e] = (_Float16)gg;
            }
            half8* gp = (half8*)&gA_s[row * 32];
            half8 z8 = {0,0,0,0,0,0,0,0};
            gp[0] = pg; gp[1] = z8; gp[2] = z8; gp[3] = z8;
        }
    }
    __syncthreads();

    // ---------------- phase 3: acc init = bias term via MFMA -------------
    f32x4 acc[4][4];
    const f32x4 zq = {0.f, 0.f, 0.f, 0.f};
    {
        half8 ga[4];
        #pragma unroll
        for (int m = 0; m < 4; ++m)
            ga[m] = *(const half8*)&gA_s[(t0w + m * 16 + r16) * 32 + q * 8];
        #pragma unroll
        for (int n = 0; n < 4; ++n) {
            const half8 bf = *(const half8*)&bB_s[(wn * 64 + n * 16 + r16) * 32 + q * 8];
            #pragma unroll
            for (int m = 0; m < 4; ++m)
                acc[m][n] = __builtin_amdgcn_mfma_f32_16x16x32_f16(ga[m], bf, zq, 0, 0, 0);
        }
    }

    // ---------------- write wb[0] (swizzled) -----------------------------
    #pragma unroll
    for (int it = 0; it < 4; ++it) {
        int v = it * 512 + tid;
        int f = v >> 4, slot = v & 15;
        char* dst = (char*)wb_s[0] + f * 256 + ((slot * 16) ^ ((f & 7) << 4));
        half8 pk;
        pk[0]=(_Float16)st[it][0][0]; pk[1]=(_Float16)st[it][0][1];
        pk[2]=(_Float16)st[it][0][2]; pk[3]=(_Float16)st[it][0][3];
        pk[4]=(_Float16)st[it][1][0]; pk[5]=(_Float16)st[it][1][1];
        pk[6]=(_Float16)st[it][1][2]; pk[7]=(_Float16)st[it][1][3];
        *(half8*)dst = pk;
    }
    __syncthreads();

    // ---------------- phase 4: dense expert loop (double-buffered) -------
    for (int e = 0; e < 8; ++e) {
        _Float16* wcur = wb_s[e & 1];
        _Float16* wnxt = wb_s[(e & 1) ^ 1];

        if (e < 7) {                                  // issue next W loads early
            const f32x4* wsrc = (const f32x4*)(W + (long)(e + 1) * 16384);
            #pragma unroll
            for (int it = 0; it < 4; ++it) {
                int v = it * 512 + tid;
                st[it][0] = wsrc[v * 2 + 0];
                st[it][1] = wsrc[v * 2 + 1];
            }
        }

        f32x4 cv[4];                                  // masked gate weights, rows q*4+r
        #pragma unroll
        for (int m = 0; m < 4; ++m)
            cv[m] = *(const f32x4*)&c_s[e][t0w + m * 16 + q * 4];

        #pragma unroll
        for (int n = 0; n < 4; ++n) {
            const int fbase = wn * 64 + n * 16 + r16; // B-col = lane&15
            const char* wrow = (const char*)wcur + fbase * 256;
            const int sw = (fbase & 7) << 4;
            f32x4 tmp[4];
            #pragma unroll
            for (int k = 0; k < 4; ++k) {
                const half8 bf = *(const half8*)(wrow + ((k * 64 + q * 16) ^ sw));
                #pragma unroll
                for (int m = 0; m < 4; ++m)
                    tmp[m] = __builtin_amdgcn_mfma_f32_16x16x32_f16(
                                 af[m][k], bf, (k == 0) ? zq : tmp[m], 0, 0, 0);
            }
            #pragma unroll
            for (int m = 0; m < 4; ++m) {
                acc[m][n][0] += cv[m][0] * tmp[m][0];
                acc[m][n][1] += cv[m][1] * tmp[m][1];
                acc[m][n][2] += cv[m][2] * tmp[m][2];
                acc[m][n][3] += cv[m][3] * tmp[m][3];
            }
        }

        if (e < 7) {                                  // write next buffer, one barrier
            #pragma unroll
            for (int it = 0; it < 4; ++it) {
                int v = it * 512 + tid;
                int f = v >> 4, slot = v & 15;
                char* dst = (char*)wnxt + f * 256 + ((slot * 16) ^ ((f & 7) << 4));
                half8 pk;
                pk[0]=(_Float16)st[it][0][0]; pk[1]=(_Float16)st[it][0][1];
                pk[2]=(_Float16)st[it][0][2]; pk[3]=(_Float16)st[it][0][3];
                pk[4]=(_Float16)st[it][1][0]; pk[5]=(_Float16)st[it][1][1];
                pk[6]=(_Float16)st[it][1][2]; pk[7]=(_Float16)st[it][1][3];
                *(half8*)dst = pk;
            }
            __syncthreads();
        }
    }

    // ---------------- phase 5: store ------------------------------------
    #pragma unroll
    for (int m = 0; m < 4; ++m) {
        const long trow = tb + t0w + m * 16 + q * 4;  // D-row = (lane>>4)*4 + r
        #pragma unroll
        for (int r = 0; r < 4; ++r) {
            float* orow = out + (trow + r) * 128 + wn * 64 + r16;
            orow[0]  = acc[m][0][r];
            orow[16] = acc[m][1][r];
            orow[32] = acc[m][2][r];
            orow[48] = acc[m][3][r];
        }
    }
}

extern "C" void kernel_launch(void* const* d_in, const int* in_sizes, int n_in,
                              void* d_out, int out_size, void* d_ws, size_t ws_size,
                              hipStream_t stream) {
    const float* x  = (const float*)d_in[0];
    const float* gW = (const float*)d_in[1];
    const float* gb = (const float*)d_in[2];
    const float* W  = (const float*)d_in[3];
    const float* b  = (const float*)d_in[4];
    float* out = (float*)d_out;
    (void)in_sizes; (void)n_in; (void)out_size; (void)d_ws; (void)ws_size;

    moe_fused<<<dim3(N_TOK / TPB), dim3(512), 0, stream>>>(x, gW, gb, W, b, out);
}

// Round 3
// 1981.685 us; speedup vs baseline: 1.0627x; 1.0627x over previous
//
#include <hip/hip_runtime.h>

// MoE fused kernel, MI355X (gfx950).
// N=524288 tokens, D=128, E=8, top-2 routing.
// Strategy: dense all-8-expert f16 MFMA with fp32 masked-gate fold in epilogue.
//
// R2 post-mortem: VGPR_Count=128 forced ~60-reg spill -> 6.1 GB scratch HBM
// traffic (FETCH 2.9 GB / WRITE 3.5 GB), dur 1931 us. Fixes:
//  (1) amdgpu_waves_per_eu(2,2): LDS=102KB already caps at 1 block/CU
//      (= 2 waves/SIMD), so pin allocator to the 256-VGPR budget.
//  (2) W staged via global_load_lds DMA from a pre-converted f16 copy in
//      d_ws (pre-kernel) -> removes 32-reg st[] staging + pack VALU.
//      LDS XOR-swizzle preserved by pre-swizzling the global SOURCE slot
//      (u^(f&7)), DMA dest linear (m173 pattern). Read path unchanged.

typedef _Float16 half8 __attribute__((ext_vector_type(8)));
typedef _Float16 half4 __attribute__((ext_vector_type(4)));
typedef float    f32x4 __attribute__((ext_vector_type(4)));

#define N_TOK   524288
#define TPB     256      // tokens per block

__device__ __forceinline__ void async_load16(const void* g, void* l) {
    __builtin_amdgcn_global_load_lds(
        (const __attribute__((address_space(1))) unsigned int*)g,
        (__attribute__((address_space(3))) unsigned int*)l, 16, 0, 0);
}

// ---- pre-kernel: W fp32 -> f16, linear [e][f][d] into d_ws (256 KB) ----
__global__ __launch_bounds__(256)
void convert_w(const float* __restrict__ W, _Float16* __restrict__ Wh) {
    const int i = blockIdx.x * 256 + threadIdx.x;   // 32768 threads, 4 elems each
    f32x4 v = ((const f32x4*)W)[i];
    half4 h;
    h[0] = (_Float16)v[0]; h[1] = (_Float16)v[1];
    h[2] = (_Float16)v[2]; h[3] = (_Float16)v[3];
    ((half4*)Wh)[i] = h;
}

__global__ __launch_bounds__(512) __attribute__((amdgpu_waves_per_eu(2, 2)))
void moe_fused(const float* __restrict__ x,
               const float* __restrict__ gW,
               const float* __restrict__ gb,
               const _Float16* __restrict__ Wh,
               const float* __restrict__ b,
               float* __restrict__ out)
{
    const int tid  = threadIdx.x;
    const int lane = tid & 63;
    const int wid  = tid >> 6;      // 0..7
    const int wm   = wid >> 1;      // 0..3 : which 64-token group
    const int wn   = wid & 1;       // 0..1 : which 64-feature half
    const int r16  = lane & 15;     // A-row / B-col / D-col within tile
    const int q    = lane >> 4;     // 0..3 : k-group (k = q*8..q*8+7)

    const int  t0w = wm * 64;                       // token offset in block
    const long tb  = (long)blockIdx.x * TPB;        // block token base

    __shared__ __align__(16) float     gW_s[8 * 128];          // 4 KB
    __shared__             float       gb_s[8];
    __shared__ __align__(16) float     c_s[8][256];            // 8 KB  masked gate weights
    __shared__ __align__(16) _Float16  gA_s[256 * 32];         // 16 KB g (all experts), K-padded to 32
    __shared__ __align__(16) _Float16  bB_s[128 * 32];         // 8 KB  b as B-operand, K-padded
    __shared__ __align__(16) _Float16  wb_s[2][128 * 128];     // 64 KB W_e double buffer (swizzled)

    // DMA-stage expert e's f16 W into wb_s[bufidx], source-preswizzled.
    // LDS content: wb[f*256B + u*16B] = W[e][f][(u^(f&7))*8 .. +7]
    auto stage = [&](int e, int bufidx) {
        const _Float16* base = Wh + e * 16384;
        char* lbase = (char*)wb_s[bufidx];
        #pragma unroll
        for (int it = 0; it < 4; ++it) {
            const int v = it * 512 + tid;            // 16B slot 0..2047
            const int f = v >> 4, u = v & 15;
            async_load16(base + f * 128 + ((u ^ (f & 7)) * 8), lbase + v * 16);
        }
    };

    // ---------------- phase 0: stage gate weights / bias ----------------
    ((float2*)gW_s)[tid] = ((const float2*)gW)[tid];   // 1024 floats
    if (tid < 8) gb_s[tid] = gb[tid];
    for (int i = tid; i < 128 * 32; i += 512) {
        int f = i >> 5, k = i & 31;
        bB_s[i] = (k < 8) ? (_Float16)b[k * 128 + f] : (_Float16)0.f;
    }

    // issue expert-0 W DMA now; it lands before the phase-3 barrier drain
    stage(0, 0);
    __syncthreads();

    // ---------------- phase 1: load x -> f16 A-frags + fp32 gate partials
    half8 af[4][4];
    float plog[4][8];
    #pragma unroll
    for (int m = 0; m < 4; ++m)
        #pragma unroll
        for (int e = 0; e < 8; ++e) plog[m][e] = 0.f;

    #pragma unroll
    for (int m = 0; m < 4; ++m) {
        const long tok = tb + t0w + m * 16 + r16;    // A-frag row = lane&15
        const float* xr = x + tok * 128;
        #pragma unroll
        for (int k = 0; k < 4; ++k) {
            const int col = k * 32 + q * 8;          // A-frag k = (lane>>4)*8 + j
            f32x4 v0 = *(const f32x4*)(xr + col);
            f32x4 v1 = *(const f32x4*)(xr + col + 4);
            half8 pk;
            pk[0]=(_Float16)v0[0]; pk[1]=(_Float16)v0[1]; pk[2]=(_Float16)v0[2]; pk[3]=(_Float16)v0[3];
            pk[4]=(_Float16)v1[0]; pk[5]=(_Float16)v1[1]; pk[6]=(_Float16)v1[2]; pk[7]=(_Float16)v1[3];
            af[m][k] = pk;
            #pragma unroll
            for (int e = 0; e < 8; ++e) {            // exact fp32 gate partials
                const float* g = gW_s + e * 128 + col;
                plog[m][e] += v0[0]*g[0] + v0[1]*g[1] + v0[2]*g[2] + v0[3]*g[3]
                            + v1[0]*g[4] + v1[1]*g[5] + v1[2]*g[6] + v1[3]*g[7];
            }
        }
    }

    // ---------------- phase 2: gate reduce + softmax + top-2 -------------
    #pragma unroll
    for (int m = 0; m < 4; ++m) {
        #pragma unroll
        for (int e = 0; e < 8; ++e) {
            float v = plog[m][e];
            v += __shfl_xor(v, 16, 64);              // sum over q-groups
            v += __shfl_xor(v, 32, 64);
            plog[m][e] = v + gb_s[e];
        }
        float m1 = -1e30f; int i1 = 0;
        #pragma unroll
        for (int e = 0; e < 8; ++e) if (plog[m][e] > m1) { m1 = plog[m][e]; i1 = e; }
        float m2 = -1e30f; int i2 = (i1 == 0) ? 1 : 0;
        #pragma unroll
        for (int e = 0; e < 8; ++e) if (e != i1 && plog[m][e] > m2) { m2 = plog[m][e]; i2 = e; }
        float ge[8]; float sum = 0.f;
        #pragma unroll
        for (int e = 0; e < 8; ++e) { ge[e] = __expf(plog[m][e] - m1); sum += ge[e]; }
        const float inv = 1.f / sum;
        if (q == 0 && wn == 0) {                     // one writer per token
            const int row = t0w + m * 16 + r16;
            half8 pg;
            #pragma unroll
            for (int e = 0; e < 8; ++e) {
                float gg = ge[e] * inv;
                c_s[e][row] = (e == i1 || e == i2) ? gg : 0.f;
                pg[e] = (_Float16)gg;
            }
            half8* gp = (half8*)&gA_s[row * 32];
            half8 z8 = {0,0,0,0,0,0,0,0};
            gp[0] = pg; gp[1] = z8; gp[2] = z8; gp[3] = z8;
        }
    }
    __syncthreads();   // drains vmcnt -> wb_s[0] DMA complete, gate data visible

    // ---------------- phase 3: acc init = bias term via MFMA -------------
    f32x4 acc[4][4];
    const f32x4 zq = {0.f, 0.f, 0.f, 0.f};
    {
        half8 ga[4];
        #pragma unroll
        for (int m = 0; m < 4; ++m)
            ga[m] = *(const half8*)&gA_s[(t0w + m * 16 + r16) * 32 + q * 8];
        #pragma unroll
        for (int n = 0; n < 4; ++n) {
            const half8 bf = *(const half8*)&bB_s[(wn * 64 + n * 16 + r16) * 32 + q * 8];
            #pragma unroll
            for (int m = 0; m < 4; ++m)
                acc[m][n] = __builtin_amdgcn_mfma_f32_16x16x32_f16(ga[m], bf, zq, 0, 0, 0);
        }
    }

    // ---------------- phase 4: dense expert loop (double-buffered) -------
    for (int e = 0; e < 8; ++e) {
        const _Float16* wcur = wb_s[e & 1];

        if (e < 7) stage(e + 1, (e & 1) ^ 1);         // DMA next expert early

        f32x4 cv[4];                                  // masked gate weights, rows q*4+r
        #pragma unroll
        for (int m = 0; m < 4; ++m)
            cv[m] = *(const f32x4*)&c_s[e][t0w + m * 16 + q * 4];

        #pragma unroll
        for (int n = 0; n < 4; ++n) {
            const int fbase = wn * 64 + n * 16 + r16; // B-col = lane&15
            const char* wrow = (const char*)wcur + fbase * 256;
            const int sw = (fbase & 7) << 4;
            f32x4 tmp[4];
            #pragma unroll
            for (int k = 0; k < 4; ++k) {
                const half8 bf = *(const half8*)(wrow + ((k * 64 + q * 16) ^ sw));
                #pragma unroll
                for (int m = 0; m < 4; ++m)
                    tmp[m] = __builtin_amdgcn_mfma_f32_16x16x32_f16(
                                 af[m][k], bf, (k == 0) ? zq : tmp[m], 0, 0, 0);
            }
            #pragma unroll
            for (int m = 0; m < 4; ++m) {
                acc[m][n][0] += cv[m][0] * tmp[m][0];
                acc[m][n][1] += cv[m][1] * tmp[m][1];
                acc[m][n][2] += cv[m][2] * tmp[m][2];
                acc[m][n][3] += cv[m][3] * tmp[m][3];
            }
        }

        if (e < 7) __syncthreads();  // drains vmcnt -> next buffer ready; orders
                                     // this iter's wcur reads before its reuse
    }

    // ---------------- phase 5: store ------------------------------------
    #pragma unroll
    for (int m = 0; m < 4; ++m) {
        const long trow = tb + t0w + m * 16 + q * 4;  // D-row = (lane>>4)*4 + r
        #pragma unroll
        for (int r = 0; r < 4; ++r) {
            float* orow = out + (trow + r) * 128 + wn * 64 + r16;
            orow[0]  = acc[m][0][r];
            orow[16] = acc[m][1][r];
            orow[32] = acc[m][2][r];
            orow[48] = acc[m][3][r];
        }
    }
}

extern "C" void kernel_launch(void* const* d_in, const int* in_sizes, int n_in,
                              void* d_out, int out_size, void* d_ws, size_t ws_size,
                              hipStream_t stream) {
    const float* x  = (const float*)d_in[0];
    const float* gW = (const float*)d_in[1];
    const float* gb = (const float*)d_in[2];
    const float* W  = (const float*)d_in[3];
    const float* b  = (const float*)d_in[4];
    float* out = (float*)d_out;
    _Float16* Wh = (_Float16*)d_ws;   // needs 8*128*128*2 = 256 KB of workspace
    (void)in_sizes; (void)n_in; (void)out_size; (void)ws_size;

    convert_w<<<dim3(128), dim3(256), 0, stream>>>(W, Wh);
    moe_fused<<<dim3(N_TOK / TPB), dim3(512), 0, stream>>>(x, gW, gb, Wh, b, out);
}